// Round 4
// baseline (210.660 us; speedup 1.0000x reference)
//
#include <hip/hip_runtime.h>
#include <stdint.h>

#define B_SZ   2048
#define IN_SZ  1024
#define OUT_SZ 1024
#define Q_SZ   16
#define NZB    4                              // i-windows of 256

typedef __attribute__((ext_vector_type(8))) short short8;   // 8 bf16 (4 VGPRs)
typedef __attribute__((ext_vector_type(4))) float floatx4;  // MFMA accumulator
typedef __attribute__((ext_vector_type(2))) unsigned short u16x2;
typedef __attribute__((ext_vector_type(2))) short s16x2;

__device__ __forceinline__ unsigned short f32_to_bf16_rne(float f) {
    union { float f; uint32_t u; } v; v.f = f;
    uint32_t u = v.u;
    return (unsigned short)((u + 0x7FFFu + ((u >> 16) & 1u)) >> 16);
}

// packed 2x16-bit: out = (onehot has bit q) ? xv16 : 0, in 3 VALU ops.
__device__ __forceinline__ uint32_t mask3(uint32_t xv, uint32_t ohv, unsigned short sh) {
    union { uint32_t u; u16x2 v; s16x2 s; } t;
    t.u = ohv;
    u16x2 shv; shv.x = sh; shv.y = sh;
    t.v = t.v << shv;
    s16x2 f15; f15.x = 15; f15.y = 15;
    t.s = t.s >> f15;
    return xv & t.u;
}

// async global->LDS, 16B per lane, linear (wave-uniform base + lane*16)
__device__ __forceinline__ void gload_lds16(const void* g, void* l) {
    __builtin_amdgcn_global_load_lds(
        (const __attribute__((address_space(1))) unsigned int*)g,
        (__attribute__((address_space(3))) unsigned int*)l, 16, 0, 0);
}

// ---------------- prep: fragment-linear Wf (LDS-transpose, coalesced) -------
// Slab S = (zb*8+xb)*64 + ih*16 + q; chunk c = (h*8+nt)*64 + L; element j:
//   o = xb*128 + nt*16 + (L&15),  i = zb*256 + ih*64 + h*32 + (L>>4)*8 + j
__global__ void k_build_wf(const float* __restrict__ W, unsigned short* __restrict__ Wf) {
    const int S = blockIdx.x;
    const int q = S & 15, ih = (S >> 4) & 3, xb = (S >> 6) & 7, zb = S >> 9;
    const int t = threadIdx.x;
    const int i0 = zb * 256 + ih * 64;
    const int o0 = xb * 128;
    __shared__ unsigned short lds[64][130];    // pad 130: both phases ~2-way banks

#pragma unroll
    for (int it = 0; it < 8; ++it) {
        int r  = it * 8 + (t >> 5);
        int c4 = (t & 31) * 4;
        float4 v = *(const float4*)(W + ((size_t)(q * 1024 + i0 + r)) * 1024 + o0 + c4);
        unsigned short h0 = f32_to_bf16_rne(v.x), h1 = f32_to_bf16_rne(v.y);
        unsigned short h2 = f32_to_bf16_rne(v.z), h3 = f32_to_bf16_rne(v.w);
        *(uint32_t*)&lds[r][c4]     = (uint32_t)h0 | ((uint32_t)h1 << 16);
        *(uint32_t*)&lds[r][c4 + 2] = (uint32_t)h2 | ((uint32_t)h3 << 16);
    }
    __syncthreads();

    unsigned short* dst = Wf + (size_t)S * 8192;
#pragma unroll
    for (int it = 0; it < 4; ++it) {
        int c = it * 256 + t;
        int L = c & 63;
        int hnt = c >> 6;
        int h = hnt >> 3, nt = hnt & 7;
        int ol = nt * 16 + (L & 15);
        int il = h * 32 + (L >> 4) * 8;
        unsigned short v[8];
#pragma unroll
        for (int j = 0; j < 8; ++j) v[j] = lds[il + j][ol];
        *(uint4*)(dst + (size_t)c * 8) = *(uint4*)v;
    }
}

// ---------------- fused GEMM: LDS-staged B, 64b x 64o waves ------------------
// Block: 128b x 128o x (i-window 256, all 16 q) -> 64 slabs.
// Wave tile = 64b x 64o (wr = wave>>1 picks b-half, wc = wave&1 picks o-half):
// each wave reads only its 8 KB o-half of the 16 KB slab. LDS traffic per
// slab-pair per CU drops 160 KB -> 96 KB (the R2/R3 wall: redundant full-slab
// reads by all 4 waves saturated the ~85 B/cy LDS read pipe). MFMA/wave
// unchanged (4mt x 4nt x 2h = 32). 2-deep ring + syncthreads per slab (R3
// showed counted vmcnt is neutral here); both halves' ds_reads issued up
// front so h1 reads hide under h0 MFMAs via compiler lgkmcnt pipelining.
__global__ __launch_bounds__(256, 2) void k_gemm(const unsigned short* __restrict__ Wf,
                                                 const float* __restrict__ x,
                                                 const int* __restrict__ idx,
                                                 float* __restrict__ P) {
    const int tid  = threadIdx.x;
    const int wave = tid >> 6, lane = tid & 63;
    const int wr = wave >> 1, wc = wave & 1;

    // id = zb + 4*xb + 32*yb -> XCD (id%8) = zb+4*(xb&1), constant per window.
    const int id = blockIdx.x;
    const int zb = id & 3;
    const int xb = (id >> 2) & 7;
    const int yb = id >> 5;
    const int o0 = xb * 128, b0 = yb * 128, ibase = zb * 256;

    const char* wbase = (const char*)Wf + (size_t)(zb * 8 + xb) * 64 * 16384;
    const int   lofs  = lane * 16;

    __shared__ unsigned char sm[2][16384];     // 2-deep slab ring

    const int arow = b0 + wr * 64 + (lane & 15);
    const float* xg = x + (size_t)arow * IN_SZ + ibase + (lane >> 4) * 8;
    const int*   ig = idx + (size_t)arow * IN_SZ + ibase + (lane >> 4) * 8;

    floatx4 acc[16];
#pragma unroll
    for (int i = 0; i < 16; ++i) acc[i] = (floatx4){0.f, 0.f, 0.f, 0.f};

    uint4 xr[4][2], oh[4][2];                  // 64 rows x 64 i packed A state

#define RELOADA(ih)                                                           \
    {   int io_ = (ih) * 64;                                                  \
        _Pragma("unroll")                                                     \
        for (int mt_ = 0; mt_ < 4; ++mt_)                                     \
            _Pragma("unroll")                                                 \
            for (int hh_ = 0; hh_ < 2; ++hh_) {                               \
                const float* xp_ = xg + mt_ * 16 * IN_SZ + io_ + hh_ * 32;    \
                const int*   ip_ = ig + mt_ * 16 * IN_SZ + io_ + hh_ * 32;    \
                float a_[8]; int b_[8];                                       \
                *(float4*)(a_)     = *(const float4*)xp_;                     \
                *(float4*)(a_ + 4) = *((const float4*)xp_ + 1);               \
                *(int4*)(b_)       = *(const int4*)ip_;                       \
                *(int4*)(b_ + 4)   = *((const int4*)ip_ + 1);                 \
                unsigned short xv_[8];                                        \
                _Pragma("unroll")                                             \
                for (int j_ = 0; j_ < 8; ++j_) xv_[j_] = f32_to_bf16_rne(a_[j_]); \
                xr[mt_][hh_] = *(uint4*)xv_;                                  \
                uint32_t iw_[4];                                              \
                _Pragma("unroll")                                             \
                for (int w_ = 0; w_ < 4; ++w_)                                \
                    iw_[w_] = (1u << b_[2 * w_]) | ((1u << b_[2 * w_ + 1]) << 16); \
                oh[mt_][hh_] = *(uint4*)iw_;                                  \
            }                                                                 \
    }

#define MASKS(hh)                                                             \
        _Pragma("unroll")                                                     \
        for (int mt_ = 0; mt_ < 4; ++mt_) {                                   \
            aF[mt_].u.x = mask3(xr[mt_][hh].x, oh[mt_][hh].x, sh_);           \
            aF[mt_].u.y = mask3(xr[mt_][hh].y, oh[mt_][hh].y, sh_);           \
            aF[mt_].u.z = mask3(xr[mt_][hh].z, oh[mt_][hh].z, sh_);           \
            aF[mt_].u.w = mask3(xr[mt_][hh].w, oh[mt_][hh].w, sh_);           \
        }

    // each wave stages 4KB of the 16KB slab: 4 x global_load_lds(16B)
    const int soff = wave * 4096 + lofs;
#define STAGE(s_, pb_)                                                        \
    {   const char* gp_ = wbase + (size_t)(s_) * 16384 + soff;                \
        unsigned char* lp_ = &sm[pb_][soff];                                  \
        gload_lds16(gp_,        lp_);                                         \
        gload_lds16(gp_ + 1024, lp_ + 1024);                                  \
        gload_lds16(gp_ + 2048, lp_ + 2048);                                  \
        gload_lds16(gp_ + 3072, lp_ + 3072);                                  \
    }

    RELOADA(0);
    STAGE(0, 0);
    __syncthreads();                           // stage(0) complete (vmcnt drain)

#pragma unroll 1
    for (int s = 0; s < 64; ++s) {
        const int rc = s & 1;
        if (s < 63) STAGE(s + 1, rc ^ 1);
        if (s && (s & 15) == 0) RELOADA(s >> 4);
        const unsigned short sh_ = (unsigned short)(15 - (s & 15));
        union { uint4 u; short8 s8; } aF[4];

        // wave's o-half: wc selects nt-chunk 0..3 or 4..7 (each 4 KB per h)
        const unsigned char* bp = &sm[rc][wc * 4096 + lofs];
        short8 f0[4], f1[4];
#pragma unroll
        for (int nt = 0; nt < 4; ++nt) f0[nt] = *(const short8*)(bp + nt * 1024);
#pragma unroll
        for (int nt = 0; nt < 4; ++nt) f1[nt] = *(const short8*)(bp + 8192 + nt * 1024);

        MASKS(0);
#pragma unroll
        for (int mt = 0; mt < 4; ++mt)
#pragma unroll
            for (int nt = 0; nt < 4; ++nt)
                acc[mt * 4 + nt] = __builtin_amdgcn_mfma_f32_16x16x32_bf16(
                    aF[mt].s8, f0[nt], acc[mt * 4 + nt], 0, 0, 0);

        MASKS(1);
#pragma unroll
        for (int mt = 0; mt < 4; ++mt)
#pragma unroll
            for (int nt = 0; nt < 4; ++nt)
                acc[mt * 4 + nt] = __builtin_amdgcn_mfma_f32_16x16x32_bf16(
                    aF[mt].s8, f1[nt], acc[mt * 4 + nt], 0, 0, 0);

        __syncthreads();
    }

    // epilogue: plain stores to private partial buffer (C/D: col=lane&15 -> o,
    // row=(lane>>4)*4+e -> b). No atomics anywhere.
    float* Pz = P + (size_t)zb * (B_SZ * OUT_SZ);
    int cn = lane & 15, rq = lane >> 4;
#pragma unroll
    for (int mt = 0; mt < 4; ++mt)
#pragma unroll
        for (int nt = 0; nt < 4; ++nt) {
            int bb = b0 + wr * 64 + mt * 16 + rq * 4;
            int oo = o0 + wc * 64 + nt * 16 + cn;
#pragma unroll
            for (int e = 0; e < 4; ++e)
                Pz[(size_t)(bb + e) * OUT_SZ + oo] = acc[mt * 4 + nt][e];
        }
#undef RELOADA
#undef MASKS
#undef STAGE
}

// ---------------- reduce: out = bias + sum_z P[z] ----------------
__global__ void k_reduce(const float* __restrict__ P, const float* __restrict__ bias,
                         float* __restrict__ out) {
    int t = blockIdx.x * 256 + threadIdx.x;    // float4 index, 524288 total
    const float4* b4 = (const float4*)bias;
    float4 a = b4[t & 255];
#pragma unroll
    for (int z = 0; z < NZB; ++z) {
        float4 v = ((const float4*)P)[(size_t)z * (B_SZ * OUT_SZ / 4) + t];
        a.x += v.x; a.y += v.y; a.z += v.z; a.w += v.w;
    }
    ((float4*)out)[t] = a;
}

// ---------------- fallback (ws too small): exact fp32 gather ----------------
__global__ void k_naive(const float* __restrict__ x, const int* __restrict__ idx,
                        const float* __restrict__ W, const float* __restrict__ bias,
                        float* __restrict__ out) {
    int b = blockIdx.x;
    int o = threadIdx.x * 4;
    float4 acc = *(const float4*)(bias + o);
    const float* xr = x + (size_t)b * IN_SZ;
    const int*   ir = idx + (size_t)b * IN_SZ;
    for (int i = 0; i < IN_SZ; ++i) {
        float xv = xr[i];
        int q = ir[i];
        float4 w4 = *(const float4*)(W + ((size_t)q * IN_SZ + i) * OUT_SZ + o);
        acc.x += xv * w4.x; acc.y += xv * w4.y;
        acc.z += xv * w4.z; acc.w += xv * w4.w;
    }
    *(float4*)(out + (size_t)b * OUT_SZ + o) = acc;
}

extern "C" void kernel_launch(void* const* d_in, const int* in_sizes, int n_in,
                              void* d_out, int out_size, void* d_ws, size_t ws_size,
                              hipStream_t stream) {
    const float* x    = (const float*)d_in[0];
    const int*   idx  = (const int*)d_in[1];
    const float* W    = (const float*)d_in[2];
    const float* bias = (const float*)d_in[3];
    float* out = (float*)d_out;

    const size_t wf_bytes = (size_t)2048 * 16384;                 // 32 MB frag-linear W
    const size_t p_bytes  = (size_t)NZB * B_SZ * OUT_SZ * 4;      // 32 MB partials
    if (ws_size < wf_bytes + p_bytes) {
        k_naive<<<dim3(B_SZ), dim3(256), 0, stream>>>(x, idx, W, bias, out);
        return;
    }
    unsigned short* Wf = (unsigned short*)d_ws;
    float* P = (float*)((char*)d_ws + wf_bytes);

    k_build_wf<<<dim3(2048), dim3(256), 0, stream>>>(W, Wf);
    k_gemm<<<dim3(NZB * 8 * (B_SZ / 128)), dim3(256), 0, stream>>>(Wf, x, idx, P);
    k_reduce<<<dim3(2048), dim3(256), 0, stream>>>(P, bias, out);
}

// Round 5
// 205.533 us; speedup vs baseline: 1.0249x; 1.0249x over previous
//
#include <hip/hip_runtime.h>
#include <stdint.h>

#define B_SZ   2048
#define IN_SZ  1024
#define OUT_SZ 1024
#define Q_SZ   16
#define NZB    4                              // i-windows of 256

typedef __attribute__((ext_vector_type(8))) short short8;   // 8 bf16 (4 VGPRs)
typedef __attribute__((ext_vector_type(4))) float floatx4;  // MFMA accumulator
typedef __attribute__((ext_vector_type(2))) unsigned short u16x2;
typedef __attribute__((ext_vector_type(2))) short s16x2;

__device__ __forceinline__ unsigned short f32_to_bf16_rne(float f) {
    union { float f; uint32_t u; } v; v.f = f;
    uint32_t u = v.u;
    return (unsigned short)((u + 0x7FFFu + ((u >> 16) & 1u)) >> 16);
}

// packed 2x16-bit: out = (onehot has bit q) ? xv16 : 0, in 3 VALU ops.
__device__ __forceinline__ uint32_t mask3(uint32_t xv, uint32_t ohv, unsigned short sh) {
    union { uint32_t u; u16x2 v; s16x2 s; } t;
    t.u = ohv;
    u16x2 shv; shv.x = sh; shv.y = sh;
    t.v = t.v << shv;
    s16x2 f15; f15.x = 15; f15.y = 15;
    t.s = t.s >> f15;
    return xv & t.u;
}

// async global->LDS, 16B per lane, linear (wave-uniform base + lane*16)
__device__ __forceinline__ void gload_lds16(const void* g, void* l) {
    __builtin_amdgcn_global_load_lds(
        (const __attribute__((address_space(1))) unsigned int*)g,
        (__attribute__((address_space(3))) unsigned int*)l, 16, 0, 0);
}

// ---------------- prep: fragment-linear Wf (LDS-transpose, coalesced) -------
// Slab S = (zb*8+xb)*64 + ih*16 + q; chunk c = (h*8+nt)*64 + L; element j:
//   o = xb*128 + nt*16 + (L&15),  i = zb*256 + ih*64 + h*32 + (L>>4)*8 + j
__global__ void k_build_wf(const float* __restrict__ W, unsigned short* __restrict__ Wf) {
    const int S = blockIdx.x;
    const int q = S & 15, ih = (S >> 4) & 3, xb = (S >> 6) & 7, zb = S >> 9;
    const int t = threadIdx.x;
    const int i0 = zb * 256 + ih * 64;
    const int o0 = xb * 128;
    __shared__ unsigned short lds[64][130];    // pad 130: both phases ~2-way banks

#pragma unroll
    for (int it = 0; it < 8; ++it) {
        int r  = it * 8 + (t >> 5);
        int c4 = (t & 31) * 4;
        float4 v = *(const float4*)(W + ((size_t)(q * 1024 + i0 + r)) * 1024 + o0 + c4);
        unsigned short h0 = f32_to_bf16_rne(v.x), h1 = f32_to_bf16_rne(v.y);
        unsigned short h2 = f32_to_bf16_rne(v.z), h3 = f32_to_bf16_rne(v.w);
        *(uint32_t*)&lds[r][c4]     = (uint32_t)h0 | ((uint32_t)h1 << 16);
        *(uint32_t*)&lds[r][c4 + 2] = (uint32_t)h2 | ((uint32_t)h3 << 16);
    }
    __syncthreads();

    unsigned short* dst = Wf + (size_t)S * 8192;
#pragma unroll
    for (int it = 0; it < 4; ++it) {
        int c = it * 256 + t;
        int L = c & 63;
        int hnt = c >> 6;
        int h = hnt >> 3, nt = hnt & 7;
        int ol = nt * 16 + (L & 15);
        int il = h * 32 + (L >> 4) * 8;
        unsigned short v[8];
#pragma unroll
        for (int j = 0; j < 8; ++j) v[j] = lds[il + j][ol];
        *(uint4*)(dst + (size_t)c * 8) = *(uint4*)v;
    }
}

// ---------------- fused GEMM: dual-path B (h0 via LDS, h1 via L1/L2) ---------
// Block: 128b x 128o x (i-window 256, all 16 q) -> 64 slabs. Wave: 32b x 128o
// (nt=8 keeps mask-VALU at 1.5 ops/MFMA -- R4 showed 64x64 waves double it).
// R2's wall: all B through the single LDS pipe (160 KB/slab-step ~ 1880cy).
// Split: h=0 half staged to LDS (8 KB/block, shared by 4 waves); h=1 half
// read per-wave straight from global (all 8 waves/CU hit the same lines ->
// L1 broadcast). Per slab-step/CU: LDS 80 KB (~940cy) || L1/L2 64 KB ||
// MFMA 1242cy || mask-VALU ~800cy -- four pipes in parallel, none queued.
__global__ __launch_bounds__(256, 2) void k_gemm(const unsigned short* __restrict__ Wf,
                                                 const float* __restrict__ x,
                                                 const int* __restrict__ idx,
                                                 float* __restrict__ P) {
    const int tid  = threadIdx.x;
    const int wave = tid >> 6, lane = tid & 63;

    // id = zb + 4*xb + 32*yb -> XCD (id%8) = zb+4*(xb&1), constant per window.
    const int id = blockIdx.x;
    const int zb = id & 3;
    const int xb = (id >> 2) & 7;
    const int yb = id >> 5;
    const int o0 = xb * 128, b0 = yb * 128, ibase = zb * 256;

    const char* wbase = (const char*)Wf + (size_t)(zb * 8 + xb) * 64 * 16384;
    const int   lofs  = lane * 16;

    __shared__ unsigned char sm[2][8192];      // 2-deep ring, h0 halves only

    const int arow = b0 + wave * 32 + (lane & 15);
    const float* xg = x + (size_t)arow * IN_SZ + ibase + (lane >> 4) * 8;
    const int*   ig = idx + (size_t)arow * IN_SZ + ibase + (lane >> 4) * 8;

    floatx4 acc[16];
#pragma unroll
    for (int i = 0; i < 16; ++i) acc[i] = (floatx4){0.f, 0.f, 0.f, 0.f};

    uint4 xr[2][2], oh[2][2];

#define RELOADA(ih)                                                           \
    {   int io_ = (ih) * 64;                                                  \
        _Pragma("unroll")                                                     \
        for (int mt_ = 0; mt_ < 2; ++mt_)                                     \
            _Pragma("unroll")                                                 \
            for (int hh_ = 0; hh_ < 2; ++hh_) {                               \
                const float* xp_ = xg + mt_ * 16 * IN_SZ + io_ + hh_ * 32;    \
                const int*   ip_ = ig + mt_ * 16 * IN_SZ + io_ + hh_ * 32;    \
                float a_[8]; int b_[8];                                       \
                *(float4*)(a_)     = *(const float4*)xp_;                     \
                *(float4*)(a_ + 4) = *((const float4*)xp_ + 1);               \
                *(int4*)(b_)       = *(const int4*)ip_;                       \
                *(int4*)(b_ + 4)   = *((const int4*)ip_ + 1);                 \
                unsigned short xv_[8];                                        \
                _Pragma("unroll")                                             \
                for (int j_ = 0; j_ < 8; ++j_) xv_[j_] = f32_to_bf16_rne(a_[j_]); \
                xr[mt_][hh_] = *(uint4*)xv_;                                  \
                uint32_t iw_[4];                                              \
                _Pragma("unroll")                                             \
                for (int w_ = 0; w_ < 4; ++w_)                                \
                    iw_[w_] = (1u << b_[2 * w_]) | ((1u << b_[2 * w_ + 1]) << 16); \
                oh[mt_][hh_] = *(uint4*)iw_;                                  \
            }                                                                 \
    }

#define MASKS(hh)                                                             \
        _Pragma("unroll")                                                     \
        for (int mt_ = 0; mt_ < 2; ++mt_) {                                   \
            aF[mt_].u.x = mask3(xr[mt_][hh].x, oh[mt_][hh].x, sh_);           \
            aF[mt_].u.y = mask3(xr[mt_][hh].y, oh[mt_][hh].y, sh_);           \
            aF[mt_].u.z = mask3(xr[mt_][hh].z, oh[mt_][hh].z, sh_);           \
            aF[mt_].u.w = mask3(xr[mt_][hh].w, oh[mt_][hh].w, sh_);           \
        }

    // each wave stages 2KB of the 8KB h0-half: 2 x global_load_lds(16B)
    const int soff = wave * 2048 + lofs;
#define STAGE(s_, pb_)                                                        \
    {   const char* gp_ = wbase + (size_t)(s_) * 16384 + soff;                \
        unsigned char* lp_ = &sm[pb_][soff];                                  \
        gload_lds16(gp_,        lp_);                                         \
        gload_lds16(gp_ + 1024, lp_ + 1024);                                  \
    }

// one slab: h0 fragments from LDS ring buffer pc_, h1 fragments straight from
// global (issued at slab top; ~500cy of h0 mask+MFMA work hides the latency);
// stage h0 of s+1 into pn_. One barrier per slab (ring-swap + stage drain).
#define SLAB(s_, pc_, pn_)                                                    \
    {   short8 f0[8], g1[8];                                                  \
        const unsigned char* bp_ = &sm[pc_][lofs];                            \
        _Pragma("unroll")                                                     \
        for (int nt_ = 0; nt_ < 8; ++nt_)                                     \
            f0[nt_] = *(const short8*)(bp_ + nt_ * 1024);                     \
        const char* gp1_ = wbase + (size_t)(s_) * 16384 + 8192 + lofs;        \
        _Pragma("unroll")                                                     \
        for (int nt_ = 0; nt_ < 8; ++nt_)                                     \
            g1[nt_] = *(const short8*)(gp1_ + nt_ * 1024);                    \
        if ((s_) < 63) STAGE((s_) + 1, pn_);                                  \
        if ((s_) && (((s_) & 15) == 0)) RELOADA((s_) >> 4);                   \
        const unsigned short sh_ = (unsigned short)(15 - ((s_) & 15));        \
        union { uint4 u; short8 s8; } aF[2];                                  \
        MASKS(0);                                                             \
        _Pragma("unroll")                                                     \
        for (int mt_ = 0; mt_ < 2; ++mt_)                                     \
            _Pragma("unroll")                                                 \
            for (int nt_ = 0; nt_ < 8; ++nt_)                                 \
                acc[mt_ * 8 + nt_] = __builtin_amdgcn_mfma_f32_16x16x32_bf16( \
                    aF[mt_].s8, f0[nt_], acc[mt_ * 8 + nt_], 0, 0, 0);        \
        MASKS(1);                                                             \
        _Pragma("unroll")                                                     \
        for (int mt_ = 0; mt_ < 2; ++mt_)                                     \
            _Pragma("unroll")                                                 \
            for (int nt_ = 0; nt_ < 8; ++nt_)                                 \
                acc[mt_ * 8 + nt_] = __builtin_amdgcn_mfma_f32_16x16x32_bf16( \
                    aF[mt_].s8, g1[nt_], acc[mt_ * 8 + nt_], 0, 0, 0);        \
        __syncthreads();                                                      \
    }

    RELOADA(0);
    STAGE(0, 0);
    __syncthreads();                           // stage(0) complete (vmcnt drain)

#pragma unroll 1
    for (int g = 0; g < 32; ++g) {
        SLAB(2 * g,     0, 1);
        SLAB(2 * g + 1, 1, 0);
    }

    // epilogue: plain stores to private partial buffer (C/D: col=lane&15 -> o,
    // row=(lane>>4)*4+e -> b). No atomics anywhere.
    float* Pz = P + (size_t)zb * (B_SZ * OUT_SZ);
    int cn = lane & 15, rq = lane >> 4;
#pragma unroll
    for (int mt = 0; mt < 2; ++mt)
#pragma unroll
        for (int nt = 0; nt < 8; ++nt) {
            int bb = b0 + wave * 32 + mt * 16 + rq * 4;
            int oo = o0 + nt * 16 + cn;
#pragma unroll
            for (int e = 0; e < 4; ++e)
                Pz[(size_t)(bb + e) * OUT_SZ + oo] = acc[mt * 8 + nt][e];
        }
#undef RELOADA
#undef MASKS
#undef STAGE
#undef SLAB
}

// ---------------- reduce: out = bias + sum_z P[z] ----------------
__global__ void k_reduce(const float* __restrict__ P, const float* __restrict__ bias,
                         float* __restrict__ out) {
    int t = blockIdx.x * 256 + threadIdx.x;    // float4 index, 524288 total
    const float4* b4 = (const float4*)bias;
    float4 a = b4[t & 255];
#pragma unroll
    for (int z = 0; z < NZB; ++z) {
        float4 v = ((const float4*)P)[(size_t)z * (B_SZ * OUT_SZ / 4) + t];
        a.x += v.x; a.y += v.y; a.z += v.z; a.w += v.w;
    }
    ((float4*)out)[t] = a;
}

// ---------------- fallback (ws too small): exact fp32 gather ----------------
__global__ void k_naive(const float* __restrict__ x, const int* __restrict__ idx,
                        const float* __restrict__ W, const float* __restrict__ bias,
                        float* __restrict__ out) {
    int b = blockIdx.x;
    int o = threadIdx.x * 4;
    float4 acc = *(const float4*)(bias + o);
    const float* xr = x + (size_t)b * IN_SZ;
    const int*   ir = idx + (size_t)b * IN_SZ;
    for (int i = 0; i < IN_SZ; ++i) {
        float xv = xr[i];
        int q = ir[i];
        float4 w4 = *(const float4*)(W + ((size_t)q * IN_SZ + i) * OUT_SZ + o);
        acc.x += xv * w4.x; acc.y += xv * w4.y;
        acc.z += xv * w4.z; acc.w += xv * w4.w;
    }
    *(float4*)(out + (size_t)b * OUT_SZ + o) = acc;
}

extern "C" void kernel_launch(void* const* d_in, const int* in_sizes, int n_in,
                              void* d_out, int out_size, void* d_ws, size_t ws_size,
                              hipStream_t stream) {
    const float* x    = (const float*)d_in[0];
    const int*   idx  = (const int*)d_in[1];
    const float* W    = (const float*)d_in[2];
    const float* bias = (const float*)d_in[3];
    float* out = (float*)d_out;

    const size_t wf_bytes = (size_t)2048 * 16384;                 // 32 MB frag-linear W
    const size_t p_bytes  = (size_t)NZB * B_SZ * OUT_SZ * 4;      // 32 MB partials
    if (ws_size < wf_bytes + p_bytes) {
        k_naive<<<dim3(B_SZ), dim3(256), 0, stream>>>(x, idx, W, bias, out);
        return;
    }
    unsigned short* Wf = (unsigned short*)d_ws;
    float* P = (float*)((char*)d_ws + wf_bytes);

    k_build_wf<<<dim3(2048), dim3(256), 0, stream>>>(W, Wf);
    k_gemm<<<dim3(NZB * 8 * (B_SZ / 128)), dim3(256), 0, stream>>>(Wf, x, idx, P);
    k_reduce<<<dim3(2048), dim3(256), 0, stream>>>(P, bias, out);
}

// Round 6
// 191.395 us; speedup vs baseline: 1.1007x; 1.0739x over previous
//
#include <hip/hip_runtime.h>
#include <stdint.h>

#define B_SZ   2048
#define IN_SZ  1024
#define OUT_SZ 1024
#define Q_SZ   16
#define NZB    4                              // i-windows of 256

typedef __attribute__((ext_vector_type(8))) short short8;   // 8 bf16 (4 VGPRs)
typedef __attribute__((ext_vector_type(4))) float floatx4;  // MFMA accumulator
typedef __attribute__((ext_vector_type(2))) unsigned short u16x2;
typedef __attribute__((ext_vector_type(2))) short s16x2;

__device__ __forceinline__ unsigned short f32_to_bf16_rne(float f) {
    union { float f; uint32_t u; } v; v.f = f;
    uint32_t u = v.u;
    return (unsigned short)((u + 0x7FFFu + ((u >> 16) & 1u)) >> 16);
}

// packed 2x16-bit: out = (onehot has bit q) ? xv16 : 0, in 3 VALU ops.
__device__ __forceinline__ uint32_t mask3(uint32_t xv, uint32_t ohv, unsigned short sh) {
    union { uint32_t u; u16x2 v; s16x2 s; } t;
    t.u = ohv;
    u16x2 shv; shv.x = sh; shv.y = sh;
    t.v = t.v << shv;
    s16x2 f15; f15.x = 15; f15.y = 15;
    t.s = t.s >> f15;
    return xv & t.u;
}

// async global->LDS, 16B per lane, linear (wave-uniform base + lane*16)
__device__ __forceinline__ void gload_lds16(const void* g, void* l) {
    __builtin_amdgcn_global_load_lds(
        (const __attribute__((address_space(1))) unsigned int*)g,
        (__attribute__((address_space(3))) unsigned int*)l, 16, 0, 0);
}

// ---------------- prep: fragment-linear Wf (LDS-transpose, coalesced) -------
// Slab S = (zb*8+xb)*64 + ih*16 + q; chunk c = (h*8+nt)*64 + L; element j:
//   o = xb*128 + nt*16 + (L&15),  i = zb*256 + ih*64 + h*32 + (L>>4)*8 + j
__global__ void k_build_wf(const float* __restrict__ W, unsigned short* __restrict__ Wf) {
    const int S = blockIdx.x;
    const int q = S & 15, ih = (S >> 4) & 3, xb = (S >> 6) & 7, zb = S >> 9;
    const int t = threadIdx.x;
    const int i0 = zb * 256 + ih * 64;
    const int o0 = xb * 128;
    __shared__ unsigned short lds[64][130];    // pad 130: both phases ~2-way banks

#pragma unroll
    for (int it = 0; it < 8; ++it) {
        int r  = it * 8 + (t >> 5);
        int c4 = (t & 31) * 4;
        float4 v = *(const float4*)(W + ((size_t)(q * 1024 + i0 + r)) * 1024 + o0 + c4);
        unsigned short h0 = f32_to_bf16_rne(v.x), h1 = f32_to_bf16_rne(v.y);
        unsigned short h2 = f32_to_bf16_rne(v.z), h3 = f32_to_bf16_rne(v.w);
        *(uint32_t*)&lds[r][c4]     = (uint32_t)h0 | ((uint32_t)h1 << 16);
        *(uint32_t*)&lds[r][c4 + 2] = (uint32_t)h2 | ((uint32_t)h3 << 16);
    }
    __syncthreads();

    unsigned short* dst = Wf + (size_t)S * 8192;
#pragma unroll
    for (int it = 0; it < 4; ++it) {
        int c = it * 256 + t;
        int L = c & 63;
        int hnt = c >> 6;
        int h = hnt >> 3, nt = hnt & 7;
        int ol = nt * 16 + (L & 15);
        int il = h * 32 + (L >> 4) * 8;
        unsigned short v[8];
#pragma unroll
        for (int j = 0; j < 8; ++j) v[j] = lds[il + j][ol];
        *(uint4*)(dst + (size_t)c * 8) = *(uint4*)v;
    }
}

// ---------------- fused GEMM: cross-slab pipelined LDS reads -----------------
// Block: 128b x 128o x (i-window 256, all 16 q) -> 64 slabs. Wave: 32b x 128o.
// R2..R5 lesson: no pipe saturated (MFMA 1242cy, LDS 1430cy, VALU ~800cy per
// 2990cy slab-step) -- the wall is intra-slab serialization: ds_read -> lgkm
// -> masks -> MFMA inside every barrier interval, with both co-resident
// blocks phase-locking via LDS contention. Fix: every ds_read lands one
// phase before its consumer. fc[8] = h0-of-current (read during PREVIOUS
// slab); fn[8] = h1-of-current (read at slab top, consumed after masks+h0
// MFMAs ~360cy later). 4-deep LDS ring (64KB, &3 indexing), stage s+2 at
// slab s; __syncthreads drains are all covered by >=1 slab of slack.
__global__ __launch_bounds__(256, 2) void k_gemm(const unsigned short* __restrict__ Wf,
                                                 const float* __restrict__ x,
                                                 const int* __restrict__ idx,
                                                 float* __restrict__ P) {
    const int tid  = threadIdx.x;
    const int wave = tid >> 6, lane = tid & 63;

    // id = zb + 4*xb + 32*yb -> XCD (id%8) = zb+4*(xb&1), constant per window.
    const int id = blockIdx.x;
    const int zb = id & 3;
    const int xb = (id >> 2) & 7;
    const int yb = id >> 5;
    const int o0 = xb * 128, b0 = yb * 128, ibase = zb * 256;

    const char* wbase = (const char*)Wf + (size_t)(zb * 8 + xb) * 64 * 16384;
    const int   lofs  = lane * 16;

    __shared__ unsigned char sm[4][16384];     // 4-deep slab ring (64 KB)

    const int arow = b0 + wave * 32 + (lane & 15);
    const float* xg = x + (size_t)arow * IN_SZ + ibase + (lane >> 4) * 8;
    const int*   ig = idx + (size_t)arow * IN_SZ + ibase + (lane >> 4) * 8;

    floatx4 acc[16];
#pragma unroll
    for (int i = 0; i < 16; ++i) acc[i] = (floatx4){0.f, 0.f, 0.f, 0.f};

    uint4 xr[2][2], oh[2][2];
    short8 fc[8], fn[8];                       // pipelined B fragments

#define RELOADA(ih)                                                           \
    {   int io_ = (ih) * 64;                                                  \
        _Pragma("unroll")                                                     \
        for (int mt_ = 0; mt_ < 2; ++mt_)                                     \
            _Pragma("unroll")                                                 \
            for (int hh_ = 0; hh_ < 2; ++hh_) {                               \
                const float* xp_ = xg + mt_ * 16 * IN_SZ + io_ + hh_ * 32;    \
                const int*   ip_ = ig + mt_ * 16 * IN_SZ + io_ + hh_ * 32;    \
                float a_[8]; int b_[8];                                       \
                *(float4*)(a_)     = *(const float4*)xp_;                     \
                *(float4*)(a_ + 4) = *((const float4*)xp_ + 1);               \
                *(int4*)(b_)       = *(const int4*)ip_;                       \
                *(int4*)(b_ + 4)   = *((const int4*)ip_ + 1);                 \
                unsigned short xv_[8];                                        \
                _Pragma("unroll")                                             \
                for (int j_ = 0; j_ < 8; ++j_) xv_[j_] = f32_to_bf16_rne(a_[j_]); \
                xr[mt_][hh_] = *(uint4*)xv_;                                  \
                uint32_t iw_[4];                                              \
                _Pragma("unroll")                                             \
                for (int w_ = 0; w_ < 4; ++w_)                                \
                    iw_[w_] = (1u << b_[2 * w_]) | ((1u << b_[2 * w_ + 1]) << 16); \
                oh[mt_][hh_] = *(uint4*)iw_;                                  \
            }                                                                 \
    }

#define MASKS(hh)                                                             \
        _Pragma("unroll")                                                     \
        for (int mt_ = 0; mt_ < 2; ++mt_) {                                   \
            aF[mt_].u.x = mask3(xr[mt_][hh].x, oh[mt_][hh].x, sh_);           \
            aF[mt_].u.y = mask3(xr[mt_][hh].y, oh[mt_][hh].y, sh_);           \
            aF[mt_].u.z = mask3(xr[mt_][hh].z, oh[mt_][hh].z, sh_);           \
            aF[mt_].u.w = mask3(xr[mt_][hh].w, oh[mt_][hh].w, sh_);           \
        }

    // each wave stages 4KB of the 16KB slab: 4 x global_load_lds(16B)
    const int soff = wave * 4096 + lofs;
#define STAGE(s_, r_)                                                         \
    {   const char* gp_ = wbase + (size_t)(s_) * 16384 + soff;                \
        unsigned char* lp_ = (unsigned char*)sm + (r_) * 16384 + soff;        \
        gload_lds16(gp_,        lp_);                                         \
        gload_lds16(gp_ + 1024, lp_ + 1024);                                  \
        gload_lds16(gp_ + 2048, lp_ + 2048);                                  \
        gload_lds16(gp_ + 3072, lp_ + 3072);                                  \
    }

#define DSREAD(dst, rr, hofs)                                                 \
    {   const unsigned char* bp_ = (const unsigned char*)sm + (rr) * 16384 +  \
                                   (hofs) + lofs;                             \
        _Pragma("unroll")                                                     \
        for (int nt_ = 0; nt_ < 8; ++nt_)                                     \
            (dst)[nt_] = *(const short8*)(bp_ + nt_ * 1024);                  \
    }

#define MFMA16(fa)                                                            \
        _Pragma("unroll")                                                     \
        for (int mt_ = 0; mt_ < 2; ++mt_)                                     \
            _Pragma("unroll")                                                 \
            for (int nt_ = 0; nt_ < 8; ++nt_)                                 \
                acc[mt_ * 8 + nt_] = __builtin_amdgcn_mfma_f32_16x16x32_bf16( \
                    aF[mt_].s8, (fa)[nt_], acc[mt_ * 8 + nt_], 0, 0, 0);

// slab s: fn <- (s,h1) issued first; h0 MFMAs consume fc (read last slab);
// fc <- (s+1,h0) issued before h1 MFMAs; h1 MFMAs consume fn. Stage s+2.
#define SLAB(s_, rc_, rn_, rs_)                                               \
    {   if ((s_) < 62) STAGE((s_) + 2, rs_);                                  \
        DSREAD(fn, rc_, 8192);                                                \
        const unsigned short sh_ = (unsigned short)(15 - ((s_) & 15));        \
        union { uint4 u; short8 s8; } aF[2];                                  \
        MASKS(0);                                                             \
        MFMA16(fc);                                                           \
        if ((s_) < 63) DSREAD(fc, rn_, 0);                                    \
        MASKS(1);                                                             \
        MFMA16(fn);                                                           \
        __syncthreads();                                                      \
    }

    RELOADA(0);
    STAGE(0, 0);
    STAGE(1, 1);
    __syncthreads();                           // slabs 0,1 resident
    DSREAD(fc, 0, 0);                          // (0,h0)

#pragma unroll 1
    for (int gg = 0; gg < 16; ++gg) {
        if (gg && (gg & 3) == 0) RELOADA(gg >> 2);   // s = 16,32,48
        const int s0 = gg * 4;
        SLAB(s0 + 0, 0, 1, 2);
        SLAB(s0 + 1, 1, 2, 3);
        SLAB(s0 + 2, 2, 3, 0);
        SLAB(s0 + 3, 3, 0, 1);
    }

    // epilogue: plain stores to private partial buffer (C/D: col=lane&15 -> o,
    // row=(lane>>4)*4+e -> b). No atomics anywhere.
    float* Pz = P + (size_t)zb * (B_SZ * OUT_SZ);
    int cn = lane & 15, rq = lane >> 4;
#pragma unroll
    for (int mt = 0; mt < 2; ++mt)
#pragma unroll
        for (int nt = 0; nt < 8; ++nt) {
            int bb = b0 + wave * 32 + mt * 16 + rq * 4;
            int oo = o0 + nt * 16 + cn;
#pragma unroll
            for (int e = 0; e < 4; ++e)
                Pz[(size_t)(bb + e) * OUT_SZ + oo] = acc[mt * 8 + nt][e];
        }
#undef RELOADA
#undef MASKS
#undef STAGE
#undef DSREAD
#undef MFMA16
#undef SLAB
}

// ---------------- reduce: out = bias + sum_z P[z] ----------------
__global__ void k_reduce(const float* __restrict__ P, const float* __restrict__ bias,
                         float* __restrict__ out) {
    int t = blockIdx.x * 256 + threadIdx.x;    // float4 index, 524288 total
    const float4* b4 = (const float4*)bias;
    float4 a = b4[t & 255];
#pragma unroll
    for (int z = 0; z < NZB; ++z) {
        float4 v = ((const float4*)P)[(size_t)z * (B_SZ * OUT_SZ / 4) + t];
        a.x += v.x; a.y += v.y; a.z += v.z; a.w += v.w;
    }
    ((float4*)out)[t] = a;
}

// ---------------- fallback (ws too small): exact fp32 gather ----------------
__global__ void k_naive(const float* __restrict__ x, const int* __restrict__ idx,
                        const float* __restrict__ W, const float* __restrict__ bias,
                        float* __restrict__ out) {
    int b = blockIdx.x;
    int o = threadIdx.x * 4;
    float4 acc = *(const float4*)(bias + o);
    const float* xr = x + (size_t)b * IN_SZ;
    const int*   ir = idx + (size_t)b * IN_SZ;
    for (int i = 0; i < IN_SZ; ++i) {
        float xv = xr[i];
        int q = ir[i];
        float4 w4 = *(const float4*)(W + ((size_t)q * IN_SZ + i) * OUT_SZ + o);
        acc.x += xv * w4.x; acc.y += xv * w4.y;
        acc.z += xv * w4.z; acc.w += xv * w4.w;
    }
    *(float4*)(out + (size_t)b * OUT_SZ + o) = acc;
}

extern "C" void kernel_launch(void* const* d_in, const int* in_sizes, int n_in,
                              void* d_out, int out_size, void* d_ws, size_t ws_size,
                              hipStream_t stream) {
    const float* x    = (const float*)d_in[0];
    const int*   idx  = (const int*)d_in[1];
    const float* W    = (const float*)d_in[2];
    const float* bias = (const float*)d_in[3];
    float* out = (float*)d_out;

    const size_t wf_bytes = (size_t)2048 * 16384;                 // 32 MB frag-linear W
    const size_t p_bytes  = (size_t)NZB * B_SZ * OUT_SZ * 4;      // 32 MB partials
    if (ws_size < wf_bytes + p_bytes) {
        k_naive<<<dim3(B_SZ), dim3(256), 0, stream>>>(x, idx, W, bias, out);
        return;
    }
    unsigned short* Wf = (unsigned short*)d_ws;
    float* P = (float*)((char*)d_ws + wf_bytes);

    k_build_wf<<<dim3(2048), dim3(256), 0, stream>>>(W, Wf);
    k_gemm<<<dim3(NZB * 8 * (B_SZ / 128)), dim3(256), 0, stream>>>(Wf, x, idx, P);
    k_reduce<<<dim3(2048), dim3(256), 0, stream>>>(P, bias, out);
}